// Round 1
// baseline (406.722 us; speedup 1.0000x reference)
//
#include <hip/hip_runtime.h>
#include <math.h>

#define SS 2048
#define BB 32
#define HH 1024

// Kernel 1: v[b,h] = sum_o hidden[b,o] * W[o,h]   (v = hidden @ W)
// grid (HH/256, BB), block 256. W column reads coalesced; hidden row is
// wave-uniform (scalar loads).
__global__ __launch_bounds__(256) void vmat_kernel(const float* __restrict__ hidden,
                                                   const float* __restrict__ W,
                                                   float* __restrict__ v) {
    const int h = blockIdx.x * 256 + threadIdx.x;
    const int b = blockIdx.y;
    const float* __restrict__ hrow = hidden + b * HH;
    float a0 = 0.f, a1 = 0.f, a2 = 0.f, a3 = 0.f;
    for (int o = 0; o < HH; o += 4) {
        a0 = fmaf(hrow[o + 0], W[(size_t)(o + 0) * HH + h], a0);
        a1 = fmaf(hrow[o + 1], W[(size_t)(o + 1) * HH + h], a1);
        a2 = fmaf(hrow[o + 2], W[(size_t)(o + 2) * HH + h], a2);
        a3 = fmaf(hrow[o + 3], W[(size_t)(o + 3) * HH + h], a3);
    }
    v[b * HH + h] = (a0 + a1) + (a2 + a3);
}

// Kernel 2: out[b*SS + s] = v[b,:] . enc[s,b,:]
// grid (SS/16, BB), block 256 = 4 waves; each wave does 4 consecutive s.
// Lane l holds v[b, 4l .. 4l+3 (+256,+512,+768)] in registers (reused across
// the 4 s), streams enc rows with float4 loads (64 lanes x 16 B = 1 KiB/instr).
__global__ __launch_bounds__(256) void score_kernel(const float* __restrict__ enc,
                                                    const float* __restrict__ v,
                                                    float* __restrict__ out) {
    const int b = blockIdx.y;
    const int wave = threadIdx.x >> 6;
    const int lane = threadIdx.x & 63;

    const float4* __restrict__ vrow = (const float4*)(v + (size_t)b * HH);
    const float4 v0 = vrow[lane];
    const float4 v1 = vrow[lane + 64];
    const float4 v2 = vrow[lane + 128];
    const float4 v3 = vrow[lane + 192];

    const int s_base = blockIdx.x * 16 + wave * 4;
    #pragma unroll
    for (int i = 0; i < 4; ++i) {
        const int s = s_base + i;
        const float4* __restrict__ erow =
            (const float4*)(enc + (size_t)s * (BB * HH) + (size_t)b * HH);
        const float4 e0 = erow[lane];
        const float4 e1 = erow[lane + 64];
        const float4 e2 = erow[lane + 128];
        const float4 e3 = erow[lane + 192];

        float acc = 0.f;
        acc = fmaf(e0.x, v0.x, acc); acc = fmaf(e0.y, v0.y, acc);
        acc = fmaf(e0.z, v0.z, acc); acc = fmaf(e0.w, v0.w, acc);
        acc = fmaf(e1.x, v1.x, acc); acc = fmaf(e1.y, v1.y, acc);
        acc = fmaf(e1.z, v1.z, acc); acc = fmaf(e1.w, v1.w, acc);
        acc = fmaf(e2.x, v2.x, acc); acc = fmaf(e2.y, v2.y, acc);
        acc = fmaf(e2.z, v2.z, acc); acc = fmaf(e2.w, v2.w, acc);
        acc = fmaf(e3.x, v3.x, acc); acc = fmaf(e3.y, v3.y, acc);
        acc = fmaf(e3.z, v3.z, acc); acc = fmaf(e3.w, v3.w, acc);

        // wave-64 butterfly reduction
        #pragma unroll
        for (int off = 32; off >= 1; off >>= 1)
            acc += __shfl_xor(acc, off, 64);

        if (lane == 0) out[(size_t)b * SS + s] = acc;
    }
}

// Kernel 3: in-place softmax over s for each b. grid BB, block 256,
// 8 elements/thread (2048/256).
__global__ __launch_bounds__(256) void softmax_kernel(float* __restrict__ out) {
    const int b = blockIdx.x;
    float* __restrict__ row = out + (size_t)b * SS;
    const int tid = threadIdx.x;
    const int wave = tid >> 6;
    const int lane = tid & 63;

    float x[8];
    float m = -INFINITY;
    #pragma unroll
    for (int i = 0; i < 8; ++i) {
        x[i] = row[tid + 256 * i];
        m = fmaxf(m, x[i]);
    }
    #pragma unroll
    for (int off = 32; off >= 1; off >>= 1)
        m = fmaxf(m, __shfl_xor(m, off, 64));

    __shared__ float redm[4];
    __shared__ float reds[4];
    if (lane == 0) redm[wave] = m;
    __syncthreads();
    m = fmaxf(fmaxf(redm[0], redm[1]), fmaxf(redm[2], redm[3]));

    float ssum = 0.f;
    #pragma unroll
    for (int i = 0; i < 8; ++i) {
        x[i] = expf(x[i] - m);
        ssum += x[i];
    }
    #pragma unroll
    for (int off = 32; off >= 1; off >>= 1)
        ssum += __shfl_xor(ssum, off, 64);
    if (lane == 0) reds[wave] = ssum;
    __syncthreads();
    ssum = (reds[0] + reds[1]) + (reds[2] + reds[3]);

    const float inv = 1.0f / ssum;
    #pragma unroll
    for (int i = 0; i < 8; ++i)
        row[tid + 256 * i] = x[i] * inv;
}

extern "C" void kernel_launch(void* const* d_in, const int* in_sizes, int n_in,
                              void* d_out, int out_size, void* d_ws, size_t ws_size,
                              hipStream_t stream) {
    const float* hidden = (const float*)d_in[0];   // [B,H]
    const float* enc    = (const float*)d_in[1];   // [S,B,H]
    const float* W      = (const float*)d_in[2];   // [H,H] (out,in)
    // d_in[3] = bias: score[b,s] shifts by hidden[b].bias, constant in s ->
    // softmax-invariant, deliberately dropped.
    float* out = (float*)d_out;                    // [B,1,S] flat = [B,S]
    float* v   = (float*)d_ws;                     // [B,H] scratch (128 KiB)

    vmat_kernel<<<dim3(HH / 256, BB), 256, 0, stream>>>(hidden, W, v);
    score_kernel<<<dim3(SS / 16, BB), 256, 0, stream>>>(enc, v, out);
    softmax_kernel<<<BB, 256, 0, stream>>>(out);
}

// Round 3
// 369.497 us; speedup vs baseline: 1.1007x; 1.1007x over previous
//
#include <hip/hip_runtime.h>
#include <math.h>

#define SS 2048
#define BB 32
#define HH 1024
#define OCH 8          // o-chunks for split-K vmat
#define OLEN (HH/OCH)  // 128 o per chunk

typedef float v4f __attribute__((ext_vector_type(4)));  // clang-native float4

// Kernel 1 (split-K): vpart[oc][b][h] = sum_{o in chunk oc} hidden[b,o]*W[o,h]
// grid (OCH, BB), block 256. Thread t owns h=4t..4t+3 (float4 W-row loads,
// 4 KiB contiguous per block per o-step). 256 blocks -> full-chip spread,
// 128 serial o-steps with 4-deep unroll.
__global__ __launch_bounds__(256) void vmat_kernel(const float* __restrict__ hidden,
                                                   const float* __restrict__ W,
                                                   float* __restrict__ vpart) {
    const int oc = blockIdx.x;
    const int b  = blockIdx.y;
    const int t  = threadIdx.x;
    const float* __restrict__ hrow = hidden + (size_t)b * HH;
    const v4f* __restrict__ Wrow = (const v4f*)W;  // Wrow[o*256 + t]

    v4f acc = (v4f){0.f, 0.f, 0.f, 0.f};
    const int o0 = oc * OLEN;
    #pragma unroll 4
    for (int oo = 0; oo < OLEN; ++oo) {
        const int o = o0 + oo;
        const float hs = hrow[o];               // wave-uniform -> s_load
        const v4f w = Wrow[(size_t)o * 256 + t];
        acc += hs * w;
    }
    ((v4f*)(vpart + ((size_t)oc * BB + b) * HH))[t] = acc;
}

// Kernel 2: out[b*SS + s] = v[b,:] . enc[s,b,:], v folded from the 8 partials.
// grid (SS/16, BB), block 256 = 4 waves; each wave does 4 consecutive s.
__global__ __launch_bounds__(256) void score_kernel(const float* __restrict__ enc,
                                                    const float* __restrict__ vpart,
                                                    float* __restrict__ out) {
    const int b = blockIdx.y;
    const int wave = threadIdx.x >> 6;
    const int lane = threadIdx.x & 63;

    v4f v0 = (v4f){0.f,0.f,0.f,0.f}, v1 = v0, v2 = v0, v3 = v0;
    #pragma unroll
    for (int c = 0; c < OCH; ++c) {
        const v4f* __restrict__ vrow =
            (const v4f*)(vpart + ((size_t)c * BB + b) * HH);
        v0 += vrow[lane];
        v1 += vrow[lane + 64];
        v2 += vrow[lane + 128];
        v3 += vrow[lane + 192];
    }

    const int s_base = blockIdx.x * 16 + wave * 4;
    #pragma unroll
    for (int i = 0; i < 4; ++i) {
        const int s = s_base + i;
        const v4f* __restrict__ erow =
            (const v4f*)(enc + (size_t)s * (BB * HH) + (size_t)b * HH);
        // non-temporal: enc is a 256 MiB single-use stream; keep it out of L2
        const v4f e0 = __builtin_nontemporal_load(&erow[lane]);
        const v4f e1 = __builtin_nontemporal_load(&erow[lane + 64]);
        const v4f e2 = __builtin_nontemporal_load(&erow[lane + 128]);
        const v4f e3 = __builtin_nontemporal_load(&erow[lane + 192]);

        float acc = 0.f;
        acc = fmaf(e0.x, v0.x, acc); acc = fmaf(e0.y, v0.y, acc);
        acc = fmaf(e0.z, v0.z, acc); acc = fmaf(e0.w, v0.w, acc);
        acc = fmaf(e1.x, v1.x, acc); acc = fmaf(e1.y, v1.y, acc);
        acc = fmaf(e1.z, v1.z, acc); acc = fmaf(e1.w, v1.w, acc);
        acc = fmaf(e2.x, v2.x, acc); acc = fmaf(e2.y, v2.y, acc);
        acc = fmaf(e2.z, v2.z, acc); acc = fmaf(e2.w, v2.w, acc);
        acc = fmaf(e3.x, v3.x, acc); acc = fmaf(e3.y, v3.y, acc);
        acc = fmaf(e3.z, v3.z, acc); acc = fmaf(e3.w, v3.w, acc);

        #pragma unroll
        for (int off = 32; off >= 1; off >>= 1)
            acc += __shfl_xor(acc, off, 64);

        if (lane == 0) out[(size_t)b * SS + s] = acc;
    }
}

// Kernel 3: in-place softmax over s for each b. grid BB, block 256.
__global__ __launch_bounds__(256) void softmax_kernel(float* __restrict__ out) {
    const int b = blockIdx.x;
    float* __restrict__ row = out + (size_t)b * SS;
    const int tid = threadIdx.x;
    const int wave = tid >> 6;
    const int lane = tid & 63;

    float x[8];
    float m = -INFINITY;
    #pragma unroll
    for (int i = 0; i < 8; ++i) {
        x[i] = row[tid + 256 * i];
        m = fmaxf(m, x[i]);
    }
    #pragma unroll
    for (int off = 32; off >= 1; off >>= 1)
        m = fmaxf(m, __shfl_xor(m, off, 64));

    __shared__ float redm[4];
    __shared__ float reds[4];
    if (lane == 0) redm[wave] = m;
    __syncthreads();
    m = fmaxf(fmaxf(redm[0], redm[1]), fmaxf(redm[2], redm[3]));

    float ssum = 0.f;
    #pragma unroll
    for (int i = 0; i < 8; ++i) {
        x[i] = expf(x[i] - m);
        ssum += x[i];
    }
    #pragma unroll
    for (int off = 32; off >= 1; off >>= 1)
        ssum += __shfl_xor(ssum, off, 64);
    if (lane == 0) reds[wave] = ssum;
    __syncthreads();
    ssum = (reds[0] + reds[1]) + (reds[2] + reds[3]);

    const float inv = 1.0f / ssum;
    #pragma unroll
    for (int i = 0; i < 8; ++i)
        row[tid + 256 * i] = x[i] * inv;
}

extern "C" void kernel_launch(void* const* d_in, const int* in_sizes, int n_in,
                              void* d_out, int out_size, void* d_ws, size_t ws_size,
                              hipStream_t stream) {
    const float* hidden = (const float*)d_in[0];   // [B,H]
    const float* enc    = (const float*)d_in[1];   // [S,B,H]
    const float* W      = (const float*)d_in[2];   // [H,H] (out,in)
    // d_in[3] = bias: shifts score[b,:] uniformly -> softmax-invariant, dropped.
    float* out   = (float*)d_out;                  // [B,1,S] flat = [B,S]
    float* vpart = (float*)d_ws;                   // [OCH][B][H] partials (1 MiB)

    vmat_kernel<<<dim3(OCH, BB), 256, 0, stream>>>(hidden, W, vpart);
    score_kernel<<<dim3(SS / 16, BB), 256, 0, stream>>>(enc, vpart, out);
    softmax_kernel<<<BB, 256, 0, stream>>>(out);
}

// Round 4
// 353.711 us; speedup vs baseline: 1.1499x; 1.0446x over previous
//
#include <hip/hip_runtime.h>
#include <math.h>

#define SS 2048
#define BB 32
#define HH 1024
#define OCH 16          // o-chunks for split-K vmat
#define OLEN (HH/OCH)   // 64 o per chunk

typedef float v4f __attribute__((ext_vector_type(4)));  // clang-native float4

// Kernel 1 (split-K): vpart[oc][b][h] = sum_{o in chunk} hidden[b,o]*W[o,h]
// grid (OCH, BB) = 512 blocks, block 256. Thread t owns h=4t..4t+3 via float4
// W-row loads (4 KiB contiguous per block per o-step), 64 serial o-steps.
__global__ __launch_bounds__(256) void vmat_kernel(const float* __restrict__ hidden,
                                                   const float* __restrict__ W,
                                                   float* __restrict__ vpart) {
    const int oc = blockIdx.x;
    const int b  = blockIdx.y;
    const int t  = threadIdx.x;
    const float* __restrict__ hrow = hidden + (size_t)b * HH;
    const v4f* __restrict__ Wrow = (const v4f*)W;  // Wrow[o*256 + t]

    v4f acc = (v4f){0.f, 0.f, 0.f, 0.f};
    const int o0 = oc * OLEN;
    #pragma unroll 4
    for (int oo = 0; oo < OLEN; ++oo) {
        const int o = o0 + oo;
        const float hs = hrow[o];               // wave-uniform
        const v4f w = Wrow[(size_t)o * 256 + t];
        acc += hs * w;
    }
    ((v4f*)(vpart + ((size_t)oc * BB + b) * HH))[t] = acc;
}

// Kernel 1b: fold partials -> v[b,h]. grid BB, block 256 (vec4 per thread).
__global__ __launch_bounds__(256) void fold_kernel(const float* __restrict__ vpart,
                                                   float* __restrict__ v) {
    const int b = blockIdx.x;
    const int t = threadIdx.x;
    v4f acc = (v4f){0.f, 0.f, 0.f, 0.f};
    #pragma unroll
    for (int c = 0; c < OCH; ++c)
        acc += ((const v4f*)(vpart + ((size_t)c * BB + b) * HH))[t];
    ((v4f*)(v + (size_t)b * HH))[t] = acc;
}

// Kernel 2: out[b*SS + s] = v[b,:] . enc[s,b,:]
// grid (SS/32, BB) = 2048 blocks, block 256 = 4 waves; each wave does 8
// consecutive s. Lane l holds v[b, 4l..] in 4 float4 regs (reused across 8 s);
// enc rows streamed with non-temporal float4 loads (1 KiB/instr/wave).
__global__ __launch_bounds__(256) void score_kernel(const float* __restrict__ enc,
                                                    const float* __restrict__ v,
                                                    float* __restrict__ out) {
    const int b = blockIdx.y;
    const int wave = threadIdx.x >> 6;
    const int lane = threadIdx.x & 63;

    const v4f* __restrict__ vrow = (const v4f*)(v + (size_t)b * HH);
    const v4f v0 = vrow[lane];
    const v4f v1 = vrow[lane + 64];
    const v4f v2 = vrow[lane + 128];
    const v4f v3 = vrow[lane + 192];

    const int s_base = blockIdx.x * 32 + wave * 8;
    #pragma unroll
    for (int i = 0; i < 8; ++i) {
        const int s = s_base + i;
        const v4f* __restrict__ erow =
            (const v4f*)(enc + (size_t)s * (BB * HH) + (size_t)b * HH);
        // non-temporal: enc is a 256 MiB single-use stream; keep it out of L2
        const v4f e0 = __builtin_nontemporal_load(&erow[lane]);
        const v4f e1 = __builtin_nontemporal_load(&erow[lane + 64]);
        const v4f e2 = __builtin_nontemporal_load(&erow[lane + 128]);
        const v4f e3 = __builtin_nontemporal_load(&erow[lane + 192]);

        float acc = 0.f;
        acc = fmaf(e0.x, v0.x, acc); acc = fmaf(e0.y, v0.y, acc);
        acc = fmaf(e0.z, v0.z, acc); acc = fmaf(e0.w, v0.w, acc);
        acc = fmaf(e1.x, v1.x, acc); acc = fmaf(e1.y, v1.y, acc);
        acc = fmaf(e1.z, v1.z, acc); acc = fmaf(e1.w, v1.w, acc);
        acc = fmaf(e2.x, v2.x, acc); acc = fmaf(e2.y, v2.y, acc);
        acc = fmaf(e2.z, v2.z, acc); acc = fmaf(e2.w, v2.w, acc);
        acc = fmaf(e3.x, v3.x, acc); acc = fmaf(e3.y, v3.y, acc);
        acc = fmaf(e3.z, v3.z, acc); acc = fmaf(e3.w, v3.w, acc);

        #pragma unroll
        for (int off = 32; off >= 1; off >>= 1)
            acc += __shfl_xor(acc, off, 64);

        if (lane == 0) out[(size_t)b * SS + s] = acc;
    }
}

// Kernel 3: in-place softmax over s for each b. grid BB, block 256.
__global__ __launch_bounds__(256) void softmax_kernel(float* __restrict__ out) {
    const int b = blockIdx.x;
    float* __restrict__ row = out + (size_t)b * SS;
    const int tid = threadIdx.x;
    const int wave = tid >> 6;
    const int lane = tid & 63;

    float x[8];
    float m = -INFINITY;
    #pragma unroll
    for (int i = 0; i < 8; ++i) {
        x[i] = row[tid + 256 * i];
        m = fmaxf(m, x[i]);
    }
    #pragma unroll
    for (int off = 32; off >= 1; off >>= 1)
        m = fmaxf(m, __shfl_xor(m, off, 64));

    __shared__ float redm[4];
    __shared__ float reds[4];
    if (lane == 0) redm[wave] = m;
    __syncthreads();
    m = fmaxf(fmaxf(redm[0], redm[1]), fmaxf(redm[2], redm[3]));

    float ssum = 0.f;
    #pragma unroll
    for (int i = 0; i < 8; ++i) {
        x[i] = expf(x[i] - m);
        ssum += x[i];
    }
    #pragma unroll
    for (int off = 32; off >= 1; off >>= 1)
        ssum += __shfl_xor(ssum, off, 64);
    if (lane == 0) reds[wave] = ssum;
    __syncthreads();
    ssum = (reds[0] + reds[1]) + (reds[2] + reds[3]);

    const float inv = 1.0f / ssum;
    #pragma unroll
    for (int i = 0; i < 8; ++i)
        row[tid + 256 * i] = x[i] * inv;
}

extern "C" void kernel_launch(void* const* d_in, const int* in_sizes, int n_in,
                              void* d_out, int out_size, void* d_ws, size_t ws_size,
                              hipStream_t stream) {
    const float* hidden = (const float*)d_in[0];   // [B,H]
    const float* enc    = (const float*)d_in[1];   // [S,B,H]
    const float* W      = (const float*)d_in[2];   // [H,H] (out,in)
    // d_in[3] = bias: shifts score[b,:] uniformly -> softmax-invariant, dropped.
    float* out   = (float*)d_out;                  // [B,1,S] flat = [B,S]
    float* vpart = (float*)d_ws;                   // [OCH][B][H] (2 MiB)
    float* v     = vpart + (size_t)OCH * BB * HH;  // [B][H] (128 KiB)

    vmat_kernel<<<dim3(OCH, BB), 256, 0, stream>>>(hidden, W, vpart);
    fold_kernel<<<BB, 256, 0, stream>>>(vpart, v);
    score_kernel<<<dim3(SS / 32, BB), 256, 0, stream>>>(enc, v, out);
    softmax_kernel<<<BB, 256, 0, stream>>>(out);
}